// Round 5
// baseline (1382.928 us; speedup 1.0000x reference)
//
#include <hip/hip_runtime.h>
#include <math.h>

#define NN 50000
#define KK 12

typedef unsigned short u16;
typedef unsigned char u8;
typedef __attribute__((ext_vector_type(4))) float f32x4;
typedef __attribute__((ext_vector_type(8))) short short8;

__device__ inline u16 f2b(float x){
  union { float f; unsigned u; } v; v.f = x;
  unsigned r = v.u + 0x7fffu + ((v.u >> 16) & 1u);
  return (u16)(r >> 16);
}
__device__ inline float b2f(u16 b){
  union { unsigned u; float f; } v; v.u = ((unsigned)b) << 16; return v.f;
}
// fast softplus: v_exp_f32 + v_log_f32
__device__ inline float sp_(float x){
  return fmaxf(x, 0.f) + __logf(1.f + __expf(-fabsf(x)));
}
__device__ inline f32x4 mfma16(short8 a, short8 b, f32x4 c){
  return __builtin_amdgcn_mfma_f32_16x16x32_bf16(a, b, c, 0, 0, 0);
}
// node-local index = row/12 for row in [0,192)
__device__ inline int nl_(int row){ return (row*171) >> 11; }
// A-fragment from padded [rows][72] bf16 LDS tile
__device__ inline short8 ldfrag(const u16* lds, int base, int lane, int ks){
  return *(const short8*)&lds[(base + (lane & 15))*72 + ks*32 + (lane >> 4)*8];
}
// B-fragment straight from global W^T [64][64] bf16 (L2-hot)
__device__ inline short8 ldwfrag(const u16* wmat, int lane, int nt, int ks){
  return *(const short8*)&wmat[(nt*16 + (lane & 15))*64 + ks*32 + (lane >> 4)*8];
}
// Stage 192x64 fp32 -> bf16 LDS [192][72]
__device__ inline void stage_tile192(const float* src, u16* ldsA, int t){
  #pragma unroll
  for (int i = 0; i < 12; ++i){
    int f4 = t + i*256;
    int m = f4 >> 4, d = (f4 & 15) * 4;
    const float4 v = *(const float4*)(src + m*64 + d);
    ushort4 b; b.x = f2b(v.x); b.y = f2b(v.y); b.z = f2b(v.z); b.w = f2b(v.w);
    *(ushort4*)&ldsA[m*72 + d] = b;
  }
}

// ---- weight convert: 9 mats [64 out][64 k] bf16, W^T layout ----
__global__ void kw_conv(const float* We, const float* Wa, const float* Wv, u16* wb){
  int gid = blockIdx.x*256 + threadIdx.x;
  if (gid >= 9*4096) return;
  int mat = gid >> 12, rem = gid & 4095;
  int j = rem >> 6, d = rem & 63;
  int fam = mat / 3, part = mat % 3;
  int c = part*64 + d;
  float v;
  if (fam == 0) v = We[c*64 + j];
  else {
    const float* W = (fam == 1) ? Wa : Wv;
    v = W[(j >> 4)*3072 + c*16 + (j & 15)];   // (H,C,A), j = h*16+a
  }
  wb[mat*4096 + j*64 + d] = f2b(v);
}

// ---- mask fix (lens==0 row) + global masked count ----
__global__ void km_mask(const float* masks, float* maskf, float* stats){
  int t = threadIdx.x;
  int n = blockIdx.x*256 + t;
  float len = 0.f;
  if (n < NN){
    float row[KK];
    #pragma unroll
    for (int k = 0; k < KK; ++k){ row[k] = masks[n*KK + k]; len += row[k]; }
    if (len == 0.f){
      #pragma unroll
      for (int k = 0; k < KK; ++k) row[k] = (k == 0) ? 1.f : 0.f;
      len = 1.f;
    }
    #pragma unroll
    for (int k = 0; k < KK; ++k) maskf[n*KK + k] = row[k];
  }
  __shared__ float red[256];
  red[t] = len; __syncthreads();
  for (int s = 128; s > 0; s >>= 1){ if (t < s) red[t] += red[t + s]; __syncthreads(); }
  if (t == 0) atomicAdd(&stats[0], red[0]);
}

// ---- node projections: 6 x (node @ W_part); self fp32, nbr bf16 ----
__global__ __launch_bounds__(256,4) void kp_proj(const float* node, const u16* wb,
    float* ps_e, float* ps_a, float* ps_v, u16* pn_e, u16* pn_a, u16* pn_v){
  __shared__ u16 ldsA[64*72];
  int t = threadIdx.x;
  int node0 = blockIdx.x*64;
  #pragma unroll
  for (int i = 0; i < 4; ++i){
    int f4 = t + i*256;
    int m = f4 >> 4, d = (f4 & 15)*4;
    float4 v = make_float4(0.f,0.f,0.f,0.f);
    if (node0 + m < NN) v = *(const float4*)(node + (size_t)(node0 + m)*64 + d);
    ushort4 b; b.x=f2b(v.x); b.y=f2b(v.y); b.z=f2b(v.z); b.w=f2b(v.w);
    *(ushort4*)&ldsA[m*72 + d] = b;
  }
  __syncthreads();
  int lane = t & 63, w = t >> 6;
  int m0 = w*16;
  short8 a0 = ldfrag(ldsA, m0, lane, 0);
  short8 a1 = ldfrag(ldsA, m0, lane, 1);
  float* psArr[3] = {ps_e, ps_a, ps_v};
  u16*  pnArr[3] = {pn_e, pn_a, pn_v};
  #pragma unroll
  for (int p = 0; p < 6; ++p){
    const u16* W = wb + ((p % 3)*3 + (p / 3))*4096;
    #pragma unroll
    for (int nt = 0; nt < 4; ++nt){
      short8 b0 = ldwfrag(W, lane, nt, 0);
      short8 b1 = ldwfrag(W, lane, nt, 1);
      f32x4 acc = {0.f,0.f,0.f,0.f};
      acc = mfma16(a0, b0, acc);
      acc = mfma16(a1, b1, acc);
      int col = nt*16 + (lane & 15);
      #pragma unroll
      for (int r = 0; r < 4; ++r){
        int nrow = node0 + m0 + (lane >> 4)*4 + r;
        if (nrow < NN){
          if (p < 3) psArr[p][(size_t)nrow*64 + col] = acc[r];
          else       pnArr[p-3][(size_t)nrow*64 + col] = f2b(acc[r]);
        }
      }
    }
  }
}

// ---- e_lin masked stats ----
__global__ __launch_bounds__(256,5) void k1_estats(const float* edgef, const int* nidx,
    const float* maskf, const float* ps_e, const u16* pn_e, const float* b_edge,
    const u16* wb, float* stats){
  __shared__ u16 ldsA[192*72];
  __shared__ int rPn[192]; __shared__ u8 m8[192];
  __shared__ float sred[128];
  int t = threadIdx.x;
  int node0 = blockIdx.x*16;
  int e0 = node0*KK;
  int psb = node0*64;
  stage_tile192(edgef + (size_t)e0*64, ldsA, t);
  if (t < 192){ rPn[t] = nidx[e0 + t]*64; m8[t] = (u8)maskf[e0 + t]; }
  if (t < 128) sred[t] = 0.f;
  __syncthreads();
  int lane = t & 63, w = t >> 6;
  int cl = lane & 15;
  const u16* We_ = wb + 2*4096;
  float be4[4];
  #pragma unroll
  for (int nt = 0; nt < 4; ++nt) be4[nt] = b_edge[nt*16 + cl];
  #pragma unroll
  for (int mi = 0; mi < 3; ++mi){
    int mt = w + mi*4;
    short8 a0 = ldfrag(ldsA, mt*16, lane, 0);
    short8 a1 = ldfrag(ldsA, mt*16, lane, 1);
    #pragma unroll
    for (int nt = 0; nt < 4; ++nt){
      short8 b0 = ldwfrag(We_, lane, nt, 0);
      short8 b1 = ldwfrag(We_, lane, nt, 1);
      f32x4 acc = {0.f,0.f,0.f,0.f};
      acc = mfma16(a0, b0, acc);
      acc = mfma16(a1, b1, acc);
      int col = nt*16 + cl;
      float s = 0.f, q = 0.f;
      #pragma unroll
      for (int r = 0; r < 4; ++r){
        int row = mt*16 + (lane >> 4)*4 + r;
        float v = acc[r] + ps_e[psb + nl_(row)*64 + col] + b2f(pn_e[rPn[row] + col]) + be4[nt];
        float m = (float)m8[row];
        s += v*m; q += v*v*m;
      }
      s += __shfl_xor(s, 16); s += __shfl_xor(s, 32);
      q += __shfl_xor(q, 16); q += __shfl_xor(q, 32);
      if (lane < 16){ atomicAdd(&sred[col], s); atomicAdd(&sred[64 + col], q); }
    }
  }
  __syncthreads();
  if (t < 128) atomicAdd(&stats[64 + t], sred[t]);
}

// ---- finalize BN: A = g/sqrt(var+eps), B = b - mean*A ----
__global__ void k_fin(const float* g, const float* b, float* stats, int sumoff, int outoff, float cntfix){
  int j = threadIdx.x;
  float cnt = (cntfix > 0.f) ? cntfix : stats[0];
  float mean = stats[sumoff + j] / cnt;
  float var = stats[sumoff + 64 + j] / cnt - mean*mean;
  var = fmaxf(var, 0.f);
  float A = g[j] / sqrtf(var + 1e-5f);
  stats[outoff + j] = A;
  stats[outoff + 64 + j] = b[j] - mean*A;
}

// ---- main fused kernel: e_lin -> eu -> {h1+logits | v} -> softmax -> p ----
__global__ __launch_bounds__(256,5) void k3_main(const float* edgef, const int* nidx,
    const float* maskf, const float* ps_e, const u16* pn_e, const float* ps_a, const u16* pn_a,
    const float* ps_v, const u16* pn_v, const float* b_edge, const float* b_att1,
    const float* W_att2, const float* b_att2, const float* b_val,
    const u16* wb, float* stats, float* out_edge, float* att_out, u16* p_out){
  __shared__ u16 ldsA[192*72];
  __shared__ float ldsLA[192*4];        // logits, then att (reused)
  __shared__ int rPn[192]; __shared__ u8 m8[192];
  __shared__ float sred[128];
  int t = threadIdx.x;
  int node0 = blockIdx.x*16;
  int e0 = node0*KK;
  int psb = node0*64;
  stage_tile192(edgef + (size_t)e0*64, ldsA, t);
  if (t < 192){ rPn[t] = nidx[e0 + t]*64; m8[t] = (u8)maskf[e0 + t]; }
  if (t < 128) sred[t] = 0.f;
  __syncthreads();
  int lane = t & 63, w = t >> 6;
  int cl = lane & 15;

  // phase 1: e_lin -> edge_updated (write d_out fp32 + overwrite ldsA bf16)
  {
    const u16* W = wb + 2*4096;
    float Ae4[4], Be4[4], be4[4];
    #pragma unroll
    for (int nt = 0; nt < 4; ++nt){
      int col = nt*16 + cl;
      Ae4[nt] = stats[192 + col]; Be4[nt] = stats[256 + col]; be4[nt] = b_edge[col];
    }
    #pragma unroll
    for (int mi = 0; mi < 3; ++mi){
      int mt = w + mi*4;
      short8 a0 = ldfrag(ldsA, mt*16, lane, 0);
      short8 a1 = ldfrag(ldsA, mt*16, lane, 1);
      #pragma unroll
      for (int nt = 0; nt < 4; ++nt){
        short8 b0 = ldwfrag(W, lane, nt, 0);
        short8 b1 = ldwfrag(W, lane, nt, 1);
        f32x4 acc = {0.f,0.f,0.f,0.f};
        acc = mfma16(a0, b0, acc);
        acc = mfma16(a1, b1, acc);
        int col = nt*16 + cl;
        #pragma unroll
        for (int r = 0; r < 4; ++r){
          int row = mt*16 + (lane >> 4)*4 + r;
          float elin = acc[r] + ps_e[psb + nl_(row)*64 + col] + b2f(pn_e[rPn[row] + col]) + be4[nt];
          float ebn = Ae4[nt]*elin + Be4[nt];
          float orig = b2f(ldsA[row*72 + col]);
          float eu = sp_(orig + ebn*(float)m8[row]);
          out_edge[((size_t)e0 + row)*64 + col] = eu;
          ldsA[row*72 + col] = f2b(eu);
        }
      }
    }
  }
  __syncthreads();
  // merged phase 2+4: one pass over A-fragments; h1+logits AND v (v kept in regs)
  unsigned vpk[3][4][2];
  {
    const u16* Wa = wb + 5*4096;
    const u16* Wv = wb + 8*4096;
    float w24[4], ba4[4], bv4[4];
    #pragma unroll
    for (int nt = 0; nt < 4; ++nt){
      int col = nt*16 + cl;
      w24[nt] = W_att2[col]; ba4[nt] = b_att1[col]; bv4[nt] = b_val[col];
    }
    #pragma unroll
    for (int mi = 0; mi < 3; ++mi){
      int mt = w + mi*4;
      short8 a0 = ldfrag(ldsA, mt*16, lane, 0);
      short8 a1 = ldfrag(ldsA, mt*16, lane, 1);
      // att half
      #pragma unroll
      for (int nt = 0; nt < 4; ++nt){
        short8 b0 = ldwfrag(Wa, lane, nt, 0);
        short8 b1 = ldwfrag(Wa, lane, nt, 1);
        f32x4 acc = {0.f,0.f,0.f,0.f};
        acc = mfma16(a0, b0, acc);
        acc = mfma16(a1, b1, acc);
        int col = nt*16 + cl;
        #pragma unroll
        for (int r = 0; r < 4; ++r){
          int row = mt*16 + (lane >> 4)*4 + r;
          float h1 = sp_(acc[r] + ps_a[psb + nl_(row)*64 + col] + b2f(pn_a[rPn[row] + col]) + ba4[nt]);
          float lg = h1 * w24[nt];
          lg += __shfl_xor(lg, 1); lg += __shfl_xor(lg, 2);
          lg += __shfl_xor(lg, 4); lg += __shfl_xor(lg, 8);
          if (cl == 0) ldsLA[row*4 + nt] = lg + b_att2[nt];
        }
      }
      // val half (v -> packed bf16 regs)
      #pragma unroll
      for (int nt = 0; nt < 4; ++nt){
        short8 b0 = ldwfrag(Wv, lane, nt, 0);
        short8 b1 = ldwfrag(Wv, lane, nt, 1);
        f32x4 acc = {0.f,0.f,0.f,0.f};
        acc = mfma16(a0, b0, acc);
        acc = mfma16(a1, b1, acc);
        int col = nt*16 + cl;
        #pragma unroll
        for (int r = 0; r < 4; ++r){
          int row = mt*16 + (lane >> 4)*4 + r;
          float v = acc[r] + ps_v[psb + nl_(row)*64 + col] + b2f(pn_v[rPn[row] + col]) + bv4[nt];
          unsigned vb = (unsigned)f2b(v);
          if ((r & 1) == 0) vpk[mi][nt][r >> 1] = vb;
          else              vpk[mi][nt][r >> 1] |= (vb << 16);
        }
      }
    }
  }
  __syncthreads();
  // softmax over K per (node, head); overwrite ldsLA with att
  if (t < 64){
    int nl = t >> 2, h = t & 3;
    float lrow[KK], mrow[KK];
    #pragma unroll
    for (int k = 0; k < KK; ++k){ lrow[k] = ldsLA[(nl*KK + k)*4 + h]; mrow[k] = (float)m8[nl*KK + k]; }
    float mx = -3.0e38f;
    #pragma unroll
    for (int k = 0; k < KK; ++k) if (mrow[k] > 0.f) mx = fmaxf(mx, lrow[k]);
    float ssum = 0.f; float ee[KK];
    #pragma unroll
    for (int k = 0; k < KK; ++k){ float e = (mrow[k] > 0.f) ? __expf(lrow[k] - mx) : 0.f; ee[k] = e; ssum += e; }
    float inv = 1.f / ssum;
    #pragma unroll
    for (int k = 0; k < KK; ++k){
      float a = ee[k]*inv;
      ldsLA[(nl*KK + k)*4 + h] = a;
      if (att_out) att_out[((size_t)(node0 + nl)*KK + k)*4 + h] = a;
    }
  }
  __syncthreads();
  // p-epilogue: p = att*v from regs; masked stats; store p bf16
  {
    float s[4] = {0.f,0.f,0.f,0.f}, q[4] = {0.f,0.f,0.f,0.f};
    #pragma unroll
    for (int mi = 0; mi < 3; ++mi){
      int mt = w + mi*4;
      #pragma unroll
      for (int nt = 0; nt < 4; ++nt){
        int col = nt*16 + cl;
        #pragma unroll
        for (int r = 0; r < 4; ++r){
          int row = mt*16 + (lane >> 4)*4 + r;
          unsigned pk = vpk[mi][nt][r >> 1];
          float v = b2f((u16)((r & 1) ? (pk >> 16) : (pk & 0xffff)));
          float p = ldsLA[row*4 + nt] * v;
          float m = (float)m8[row];
          s[nt] += p*m; q[nt] += p*p*m;
          if (p_out) p_out[((size_t)e0 + row)*64 + col] = f2b(p);
        }
      }
    }
    #pragma unroll
    for (int nt = 0; nt < 4; ++nt){
      float ss = s[nt], qq = q[nt];
      ss += __shfl_xor(ss, 16); ss += __shfl_xor(ss, 32);
      qq += __shfl_xor(qq, 16); qq += __shfl_xor(qq, 32);
      if (lane < 16){ atomicAdd(&sred[nt*16 + cl], ss); atomicAdd(&sred[64 + nt*16 + cl], qq); }
    }
  }
  __syncthreads();
  if (t < 128) atomicAdd(&stats[320 + t], sred[t]);
}

// ---- k5 stream path: pool from stored p (bf16), vectorized ----
__global__ __launch_bounds__(256,8) void k5_stream(const u16* pbuf, const float* maskf,
    float* stats, float* pooled){
  __shared__ float sred[128];
  int t = threadIdx.x;
  int node0 = blockIdx.x*16;
  int n = node0 + (t >> 4);
  int cg = (t & 15)*4;
  if (t < 128) sred[t] = 0.f;
  __syncthreads();
  float Ap[4], Bp[4];
  #pragma unroll
  for (int j = 0; j < 4; ++j){ Ap[j] = stats[448 + cg + j]; Bp[j] = stats[512 + cg + j]; }
  float acc[4] = {0.f,0.f,0.f,0.f};
  #pragma unroll
  for (int k = 0; k < KK; ++k){
    float m = maskf[n*KK + k];
    ushort4 pv = *(const ushort4*)&pbuf[((size_t)(n*KK + k))*64 + cg];
    acc[0] += sp_(Ap[0]*b2f(pv.x) + Bp[0]) * m;
    acc[1] += sp_(Ap[1]*b2f(pv.y) + Bp[1]) * m;
    acc[2] += sp_(Ap[2]*b2f(pv.z) + Bp[2]) * m;
    acc[3] += sp_(Ap[3]*b2f(pv.w) + Bp[3]) * m;
  }
  *(float4*)&pooled[(size_t)n*64 + cg] = make_float4(acc[0], acc[1], acc[2], acc[3]);
  #pragma unroll
  for (int j = 0; j < 4; ++j){
    atomicAdd(&sred[cg + j], acc[j]);
    atomicAdd(&sred[64 + cg + j], acc[j]*acc[j]);
  }
  __syncthreads();
  if (t < 128) atomicAdd(&stats[576 + t], sred[t]);
}

// ---- k5 fallback: recompute v from edge_updated ----
__global__ __launch_bounds__(256,4) void k5_rec(const float* eu, const int* nidx,
    const float* maskf, const float* ps_v, const u16* pn_v, const float* b_val,
    const u16* wb, const float* att_in, float* stats, float* pooled){
  __shared__ u16 ldsA[192*72];
  __shared__ float ldsAtt[192*4];
  __shared__ float pool[16*64];
  __shared__ int rPn[192]; __shared__ u8 m8[192];
  __shared__ float sred[128];
  int t = threadIdx.x;
  int node0 = blockIdx.x*16;
  int e0 = node0*KK;
  int psb = node0*64;
  stage_tile192(eu + (size_t)e0*64, ldsA, t);
  if (t < 192){ rPn[t] = nidx[e0 + t]*64; m8[t] = (u8)maskf[e0 + t]; }
  #pragma unroll
  for (int i = 0; i < 3; ++i){ int q = t + i*256; ldsAtt[q] = att_in[(size_t)e0*4 + q]; }
  #pragma unroll
  for (int i = 0; i < 4; ++i) pool[t + i*256] = 0.f;
  if (t < 128) sred[t] = 0.f;
  __syncthreads();
  int lane = t & 63, w = t >> 6;
  int cl = lane & 15;
  const u16* W = wb + 8*4096;
  float bv4[4], Ap4[4], Bp4[4];
  #pragma unroll
  for (int nt = 0; nt < 4; ++nt){
    int col = nt*16 + cl;
    bv4[nt] = b_val[col]; Ap4[nt] = stats[448 + col]; Bp4[nt] = stats[512 + col];
  }
  #pragma unroll
  for (int mi = 0; mi < 3; ++mi){
    int mt = w + mi*4;
    short8 a0 = ldfrag(ldsA, mt*16, lane, 0);
    short8 a1 = ldfrag(ldsA, mt*16, lane, 1);
    #pragma unroll
    for (int nt = 0; nt < 4; ++nt){
      short8 b0 = ldwfrag(W, lane, nt, 0);
      short8 b1 = ldwfrag(W, lane, nt, 1);
      f32x4 acc = {0.f,0.f,0.f,0.f};
      acc = mfma16(a0, b0, acc);
      acc = mfma16(a1, b1, acc);
      int col = nt*16 + cl;
      #pragma unroll
      for (int r = 0; r < 4; ++r){
        int row = mt*16 + (lane >> 4)*4 + r;
        float v = acc[r] + ps_v[psb + nl_(row)*64 + col] + b2f(pn_v[rPn[row] + col]) + bv4[nt];
        float p = ldsAtt[row*4 + nt] * v;
        float head = sp_(Ap4[nt]*p + Bp4[nt]) * (float)m8[row];
        atomicAdd(&pool[nl_(row)*64 + col], head);
      }
    }
  }
  __syncthreads();
  int ch = t & 63;
  float s = 0.f, q = 0.f;
  #pragma unroll
  for (int i = 0; i < 4; ++i){
    int qi = t + i*256;
    float val = pool[qi];
    pooled[((size_t)(node0 + (qi >> 6)))*64 + ch] = val;
    s += val; q += val*val;
  }
  atomicAdd(&sred[ch], s); atomicAdd(&sred[64 + ch], q);
  __syncthreads();
  if (t < 128) atomicAdd(&stats[576 + t], sred[t]);
}

// ---- residual + out BN (in-place: out currently holds pooled) ----
__global__ void k7_out(const float* node, const float* stats, float* out){
  int i = blockIdx.x*256 + threadIdx.x;
  if (i < NN*64){
    int ch = i & 63;
    float pooled = out[i];
    out[i] = node[i] + stats[704 + ch]*pooled + stats[768 + ch];
  }
}

extern "C" void kernel_launch(void* const* d_in, const int* in_sizes, int n_in,
                              void* d_out, int out_size, void* d_ws, size_t ws_size,
                              hipStream_t stream){
  const float* node   = (const float*)d_in[0];
  const float* edgef  = (const float*)d_in[1];
  const int*   nidx   = (const int*)d_in[2];
  const float* masks  = (const float*)d_in[3];
  const float* We     = (const float*)d_in[4];
  const float* b_edge = (const float*)d_in[5];
  const float* g_ebn  = (const float*)d_in[6];
  const float* b_ebn  = (const float*)d_in[7];
  const float* Wa1    = (const float*)d_in[8];
  const float* b_att1 = (const float*)d_in[9];
  const float* Wa2    = (const float*)d_in[10];
  const float* b_att2 = (const float*)d_in[11];
  const float* Wv     = (const float*)d_in[12];
  const float* b_val  = (const float*)d_in[13];
  const float* g_abn  = (const float*)d_in[14];
  const float* b_abn  = (const float*)d_in[15];
  const float* g_obn  = (const float*)d_in[16];
  const float* b_obn  = (const float*)d_in[17];

  float* ps_e   = (float*)d_ws;
  float* ps_a   = ps_e   + (size_t)NN*64;
  float* ps_v   = ps_a   + (size_t)NN*64;
  float* maskf  = ps_v   + (size_t)NN*64;
  float* att    = maskf  + (size_t)NN*KK;
  float* stats  = att    + (size_t)NN*KK*4;
  u16*   pn_e   = (u16*)(stats + 1024);
  u16*   pn_a   = pn_e   + (size_t)NN*64;
  u16*   pn_v   = pn_a   + (size_t)NN*64;
  u16*   wb     = pn_v   + (size_t)NN*64;
  u16*   pbuf   = wb     + 9*4096;
  size_t need   = (size_t)((char*)(pbuf + (size_t)NN*KK*64) - (char*)d_ws);
  bool   use_p  = (ws_size >= need);   // constant per session -> graph-safe

  float* out_node = (float*)d_out;          // holds pooled between k5 and k7
  float* out_edge = out_node + (size_t)NN*64;

  hipMemsetAsync(stats, 0, 1024*sizeof(float), stream);
  kw_conv<<<144, 256, 0, stream>>>(We, Wa1, Wv, wb);
  km_mask<<<(NN + 255)/256, 256, 0, stream>>>(masks, maskf, stats);
  kp_proj<<<(NN + 63)/64, 256, 0, stream>>>(node, wb, ps_e, ps_a, ps_v, pn_e, pn_a, pn_v);
  k1_estats<<<NN/16, 256, 0, stream>>>(edgef, nidx, maskf, ps_e, pn_e, b_edge, wb, stats);
  k_fin<<<1, 64, 0, stream>>>(g_ebn, b_ebn, stats, 64, 192, 0.f);
  k3_main<<<NN/16, 256, 0, stream>>>(edgef, nidx, maskf, ps_e, pn_e, ps_a, pn_a, ps_v, pn_v,
      b_edge, b_att1, Wa2, b_att2, b_val, wb, stats, out_edge,
      use_p ? (float*)nullptr : att, use_p ? pbuf : (u16*)nullptr);
  k_fin<<<1, 64, 0, stream>>>(g_abn, b_abn, stats, 320, 448, 0.f);
  if (use_p)
    k5_stream<<<NN/16, 256, 0, stream>>>(pbuf, maskf, stats, out_node);
  else
    k5_rec<<<NN/16, 256, 0, stream>>>(out_edge, nidx, maskf, ps_v, pn_v, b_val, wb, att, stats, out_node);
  k_fin<<<1, 64, 0, stream>>>(g_obn, b_obn, stats, 576, 704, (float)NN);
  k7_out<<<(NN*64 + 255)/256, 256, 0, stream>>>(node, stats, out_node);
}